// Round 1
// baseline (77.432 us; speedup 1.0000x reference)
//
#include <hip/hip_runtime.h>

// One thread = one sample. 16 real amplitudes in registers.
// Index convention (matches (B,2,2,2,2) row-major): idx = q0*8 + q1*4 + q2*2 + q3,
// i.e. wire w <-> bit (8 >> w).

__global__ __launch_bounds__(256) void qlayer_kernel(
    const float* __restrict__ patch,   // (B,4)
    const float* __restrict__ params,  // (2,4)
    float* __restrict__ out,           // (B,4)
    int B)
{
    int b = blockIdx.x * blockDim.x + threadIdx.x;
    if (b >= B) return;

    // ---- load this sample's 4 encoding angles (coalesced 16B) ----
    const float4 pv = reinterpret_cast<const float4*>(patch)[b];

    float ec[4], es[4];
    __sincosf(pv.x * 0.5f, &es[0], &ec[0]);
    __sincosf(pv.y * 0.5f, &es[1], &ec[1]);
    __sincosf(pv.z * 0.5f, &es[2], &ec[2]);
    __sincosf(pv.w * 0.5f, &es[3], &ec[3]);

    // ---- encoding layer: |psi> = prod_i [c_i, s_i]  (sparse; ~30 muls) ----
    float st[16];
    {
        float t01[4];  // over (q0,q1)
        t01[0] = ec[0] * ec[1];
        t01[1] = ec[0] * es[1];
        t01[2] = es[0] * ec[1];
        t01[3] = es[0] * es[1];
        float t23[4];  // over (q2,q3)
        t23[0] = ec[2] * ec[3];
        t23[1] = ec[2] * es[3];
        t23[2] = es[2] * ec[3];
        t23[3] = es[2] * es[3];
#pragma unroll
        for (int i = 0; i < 16; ++i)
            st[i] = t01[i >> 2] * t23[i & 3];
    }

    // ---- variational layers ----
#pragma unroll
    for (int d = 0; d < 2; ++d) {
        // RY on each wire
#pragma unroll
        for (int w = 0; w < 4; ++w) {
            float th = params[d * 4 + w] * 0.5f;
            float sn, cs;
            __sincosf(th, &sn, &cs);
            const int BIT = 8 >> w;
#pragma unroll
            for (int i = 0; i < 16; ++i) {
                if (!(i & BIT)) {
                    float a0 = st[i], a1 = st[i | BIT];
                    st[i]       = fmaf(cs, a0, -sn * a1);
                    st[i | BIT] = fmaf(sn, a0,  cs * a1);
                }
            }
        }
        // CNOT ring (ctrl,tgt) = (0,1),(1,2),(2,3),(3,0): pure register swaps
#pragma unroll
        for (int ring = 0; ring < 4; ++ring) {
            const int CB = (ring == 0) ? 8 : (ring == 1) ? 4 : (ring == 2) ? 2 : 1;
            const int TB = (ring == 0) ? 4 : (ring == 1) ? 2 : (ring == 2) ? 1 : 8;
#pragma unroll
            for (int i = 0; i < 16; ++i) {
                if ((i & CB) && !(i & TB)) {
                    float t = st[i];
                    st[i] = st[i | TB];
                    st[i | TB] = t;
                }
            }
        }
    }

    // ---- expectation values: <Z_w> = sum_i (+/-) st[i]^2 ----
    float e0 = 0.f, e1 = 0.f, e2 = 0.f, e3 = 0.f;
#pragma unroll
    for (int i = 0; i < 16; ++i) {
        float p = st[i] * st[i];
        e0 += (i & 8) ? -p : p;
        e1 += (i & 4) ? -p : p;
        e2 += (i & 2) ? -p : p;
        e3 += (i & 1) ? -p : p;
    }

    reinterpret_cast<float4*>(out)[b] = make_float4(e0, e1, e2, e3);
}

extern "C" void kernel_launch(void* const* d_in, const int* in_sizes, int n_in,
                              void* d_out, int out_size, void* d_ws, size_t ws_size,
                              hipStream_t stream)
{
    const float* patch  = (const float*)d_in[0];
    const float* params = (const float*)d_in[1];
    float* out = (float*)d_out;

    int B = in_sizes[0] / 4;
    int block = 256;
    int grid = (B + block - 1) / block;
    qlayer_kernel<<<grid, block, 0, stream>>>(patch, params, out, B);
}

// Round 2
// 71.343 us; speedup vs baseline: 1.0853x; 1.0853x over previous
//
#include <hip/hip_runtime.h>

// One thread = one sample. 16 real amplitudes in registers.
// Index convention (matches (B,2,2,2,2) row-major): idx = q0*8 + q1*4 + q2*2 + q3,
// i.e. wire w <-> bit (8 >> w).
//
// Algebraic simplification: encode RY(x_i) followed immediately by layer-0
// RY(p0_i) on the same wire == RY(x_i + p0_i), and RYs on different wires
// commute. So the circuit is:
//   product state with angles (x_i + p0_i)  ->  CNOT ring  ->
//   dense RY(p1_i) sweep  ->  CNOT ring  ->  <Z_w>
// CNOT rings are pure register permutations (zero instructions).

__global__ __launch_bounds__(256) void qlayer_kernel(
    const float* __restrict__ patch,   // (B,4)
    const float* __restrict__ params,  // (2,4)
    float* __restrict__ out,           // (B,4)
    int B)
{
    int b = blockIdx.x * blockDim.x + threadIdx.x;
    if (b >= B) return;

    // ---- load this sample's 4 encoding angles (coalesced 16B) ----
    const float4 pv = reinterpret_cast<const float4*>(patch)[b];

    // ---- combined encode+layer0 angles; product state build (~24 muls) ----
    float ec[4], es[4];
    __sincosf((pv.x + params[0]) * 0.5f, &es[0], &ec[0]);
    __sincosf((pv.y + params[1]) * 0.5f, &es[1], &ec[1]);
    __sincosf((pv.z + params[2]) * 0.5f, &es[2], &ec[2]);
    __sincosf((pv.w + params[3]) * 0.5f, &es[3], &ec[3]);

    float st[16];
    {
        float t01[4];  // over (q0,q1)
        t01[0] = ec[0] * ec[1];
        t01[1] = ec[0] * es[1];
        t01[2] = es[0] * ec[1];
        t01[3] = es[0] * es[1];
        float t23[4];  // over (q2,q3)
        t23[0] = ec[2] * ec[3];
        t23[1] = ec[2] * es[3];
        t23[2] = es[2] * ec[3];
        t23[3] = es[2] * es[3];
#pragma unroll
        for (int i = 0; i < 16; ++i)
            st[i] = t01[i >> 2] * t23[i & 3];
    }

    // ---- CNOT ring #1: (0,1),(1,2),(2,3),(3,0) — register renames only ----
#pragma unroll
    for (int ring = 0; ring < 4; ++ring) {
        const int CB = (ring == 0) ? 8 : (ring == 1) ? 4 : (ring == 2) ? 2 : 1;
        const int TB = (ring == 0) ? 4 : (ring == 1) ? 2 : (ring == 2) ? 1 : 8;
#pragma unroll
        for (int i = 0; i < 16; ++i) {
            if ((i & CB) && !(i & TB)) {
                float t = st[i];
                st[i] = st[i | TB];
                st[i | TB] = t;
            }
        }
    }

    // ---- dense RY(p1_w) sweep (the only dense layer left: 128 VALU ops) ----
#pragma unroll
    for (int w = 0; w < 4; ++w) {
        float sn, cs;
        __sincosf(params[4 + w] * 0.5f, &sn, &cs);  // batch-uniform angle
        const int BIT = 8 >> w;
#pragma unroll
        for (int i = 0; i < 16; ++i) {
            if (!(i & BIT)) {
                float a0 = st[i], a1 = st[i | BIT];
                st[i]       = fmaf(cs, a0, -sn * a1);
                st[i | BIT] = fmaf(sn, a0,  cs * a1);
            }
        }
    }

    // ---- CNOT ring #2 ----
#pragma unroll
    for (int ring = 0; ring < 4; ++ring) {
        const int CB = (ring == 0) ? 8 : (ring == 1) ? 4 : (ring == 2) ? 2 : 1;
        const int TB = (ring == 0) ? 4 : (ring == 1) ? 2 : (ring == 2) ? 1 : 8;
#pragma unroll
        for (int i = 0; i < 16; ++i) {
            if ((i & CB) && !(i & TB)) {
                float t = st[i];
                st[i] = st[i | TB];
                st[i | TB] = t;
            }
        }
    }

    // ---- expectation values via shared pair sums/diffs (~60 ops) ----
    float p[16];
#pragma unroll
    for (int i = 0; i < 16; ++i) p[i] = st[i] * st[i];

    float q[8], d[8];
#pragma unroll
    for (int j = 0; j < 8; ++j) {
        q[j] = p[2 * j] + p[2 * j + 1];   // collapse bit0
        d[j] = p[2 * j] - p[2 * j + 1];   // signed by bit0
    }
    float e3 = ((d[0] + d[1]) + (d[2] + d[3])) + ((d[4] + d[5]) + (d[6] + d[7]));
    float e2 = ((q[0] - q[1]) + (q[2] - q[3])) + ((q[4] - q[5]) + (q[6] - q[7]));
    float e1 = ((q[0] + q[1]) - (q[2] + q[3])) + ((q[4] + q[5]) - (q[6] + q[7]));
    float e0 = ((q[0] + q[1]) + (q[2] + q[3])) - ((q[4] + q[5]) + (q[6] + q[7]));

    reinterpret_cast<float4*>(out)[b] = make_float4(e0, e1, e2, e3);
}

extern "C" void kernel_launch(void* const* d_in, const int* in_sizes, int n_in,
                              void* d_out, int out_size, void* d_ws, size_t ws_size,
                              hipStream_t stream)
{
    const float* patch  = (const float*)d_in[0];
    const float* params = (const float*)d_in[1];
    float* out = (float*)d_out;

    int B = in_sizes[0] / 4;
    int block = 256;
    int grid = (B + block - 1) / block;
    qlayer_kernel<<<grid, block, 0, stream>>>(patch, params, out, B);
}